// Round 7
// baseline (2108.291 us; speedup 1.0000x reference)
//
#include <hip/hip_runtime.h>
#include <stdint.h>

// BiLSTM-CRF forward on MI355X.
// R7: 32-WG LSTM (4-way unit split, L2 h-board all-gather, no LDS),
//     early xg prefetch, packed publishes.
typedef unsigned short u16;
typedef __attribute__((ext_vector_type(4))) float f32x4;
typedef __attribute__((ext_vector_type(8))) short short8;

#define OFF_FLAGS  ((size_t)0)           // [8 dg][512 t][4 Q] u32 = 64 KB
#define OFF_HBOARD ((size_t)65536)       // [8 dg][2 par][16 b][256 u] fp8 = 64 KB
#define OFF_BIAS   ((size_t)131072)      // 2048*4
#define OFF_WFRAG  ((size_t)262144)      // 512 KB fp8 w_hh frags
#define OFF_HHIST  ((size_t)1048576)     // [2][64][512][256] u16 = 32 MB
#define OFF_FEATS  ((size_t)34603008)    // 32768*9*4
#define OFF_XG     ((size_t)37748736)    // [32 slice][512 s][512 tid][8 bf16] = 128 MB

__device__ __forceinline__ u16 f2bf(float f) {
  union { float f; uint32_t u; } v; v.f = f;
  uint32_t u = v.u;
  return (u16)((u + 0x7fffu + ((u >> 16) & 1u)) >> 16);
}
__device__ __forceinline__ float bf2f(u16 h) {
  union { uint32_t u; float f; } v; v.u = ((uint32_t)h) << 16; return v.f;
}
__device__ __forceinline__ short8 pack8(f32x4 a, f32x4 b) {
  short8 r;
  r[0] = (short)f2bf(a[0]); r[1] = (short)f2bf(a[1]);
  r[2] = (short)f2bf(a[2]); r[3] = (short)f2bf(a[3]);
  r[4] = (short)f2bf(b[0]); r[5] = (short)f2bf(b[1]);
  r[6] = (short)f2bf(b[2]); r[7] = (short)f2bf(b[3]);
  return r;
}

// ---- combined input-gate bias ----
__global__ void bias_kernel(const float* __restrict__ bihf, const float* __restrict__ bhhf,
                            const float* __restrict__ bihb, const float* __restrict__ bhhb,
                            float* __restrict__ bias) {
  int n = blockIdx.x * 256 + threadIdx.x;
  if (n < 1024) bias[n] = bihf[n] + bhhf[n];
  else          bias[n] = bihb[n - 1024] + bhhb[n - 1024];
}

// ---- w_hh -> fp8 e4m3 B-fragments (x16 scale) ----
// flat gid = d*32768 + Q*8192 + w*1024 + t2*512 + s*64 + l  (8 bytes each)
// tile (w,t2): col c = l&15 -> gate = (c>>3)*2 + t2, unit = Q*64 + w*8 + (c&7)
// K slot s: srcQ = (s<2) ? Q : (Q + 1 + ((s-2)>>1)) & 3; half = s&1
// k_src = srcQ*64 + half*32 + (l>>4)*8 + j
__global__ void wfrag_prep_kernel(const float* __restrict__ whhf,
                                  const float* __restrict__ whhb,
                                  uint8_t* __restrict__ wfrag) {
  int gid = blockIdx.x * 256 + threadIdx.x;   // 0..65535
  const int l  = gid & 63;
  const int s  = (gid >> 6) & 7;
  const int t2 = (gid >> 9) & 1;
  const int w  = (gid >> 10) & 7;
  const int Q  = (gid >> 13) & 3;
  const int d  = (gid >> 15) & 1;
  const float* W = d ? whhb : whhf;
  const int gate = ((l & 15) >> 3) * 2 + t2;
  const int unit = Q * 64 + w * 8 + (l & 7);
  const int row  = gate * 256 + unit;
  const int srcQ = (s < 2) ? Q : ((Q + 1 + ((s - 2) >> 1)) & 3);
  const int half = s & 1;
  const int k0 = srcQ * 64 + half * 32 + (l >> 4) * 8;
  uint32_t out[2] = {0u, 0u};
  #pragma unroll
  for (int jj = 0; jj < 4; ++jj) {
    const float f0 = W[(size_t)row * 256 + k0 + jj * 2]     * 16.0f;
    const float f1 = W[(size_t)row * 256 + k0 + jj * 2 + 1] * 16.0f;
    const int pk = __builtin_amdgcn_cvt_pk_fp8_f32(f0, f1, 0, false);
    out[jj >> 1] |= (uint32_t)(pk & 0xffff) << (16 * (jj & 1));
  }
  *(uint2*)(wfrag + (size_t)gid * 8) = make_uint2(out[0], out[1]);
}

// ---- xg = gather(emb) @ w_ih^T + bias, epilogue in lstm per-lane order ----
__global__ void __launch_bounds__(256) xg_gemm_kernel(
    const int* __restrict__ sent, const float* __restrict__ emb,
    const float* __restrict__ w_ih_f, const float* __restrict__ w_ih_b,
    const float* __restrict__ bias, u16* __restrict__ xgf)
{
  extern __shared__ char smem[];
  u16*   Al    = (u16*)smem;             // [128][136]
  u16*   Bl    = (u16*)(smem + 34816);   // [128][136]
  float* biasl = (float*)(smem + 69632); // [128]
  int*   tokl  = (int*)(smem + 70144);   // [128]

  const int tid = threadIdx.x;
  const int d  = blockIdx.x >> 3, u0 = (blockIdx.x & 7) * 32;
  const int g  = blockIdx.y >> 6, qb = (blockIdx.y >> 4) & 3, s0 = (blockIdx.y & 15) * 32;
  const float* wih = d ? w_ih_b : w_ih_f;

  if (tid < 128) {
    tokl[tid]  = sent[(size_t)(g * 16 + qb * 4 + (tid & 3)) * 512 + s0 + (tid >> 2)];
    biasl[tid] = bias[d * 1024 + (tid >> 5) * 256 + u0 + (tid & 31)];
  }
  __syncthreads();

  f32x4 acc[4][4];
  #pragma unroll
  for (int i = 0; i < 4; ++i)
    #pragma unroll
    for (int j = 0; j < 4; ++j) acc[i][j] = (f32x4){0.f, 0.f, 0.f, 0.f};

  const int wv = tid >> 6, l = tid & 63;
  const int mh = (wv >> 1) * 64, nh = (wv & 1) * 64;
  const int fr = l & 15, fq = l >> 4;
  const int rr = tid >> 1, c0 = (tid & 1) * 64;

  for (int kc = 0; kc < 2; ++kc) {
    const int k0 = kc * 128;
    const float* asrc = emb + (size_t)tokl[rr] * 256 + k0 + c0;
    const float* bsrc = wih + (size_t)((rr >> 5) * 256 + u0 + (rr & 31)) * 256 + k0 + c0;
    u16* adst = Al + rr * 136 + c0;
    u16* bdst = Bl + rr * 136 + c0;
    #pragma unroll
    for (int gdx = 0; gdx < 8; ++gdx) {
      f32x4 a0 = *(const f32x4*)(asrc + gdx * 8);
      f32x4 a1 = *(const f32x4*)(asrc + gdx * 8 + 4);
      *(short8*)(adst + gdx * 8) = pack8(a0, a1);
      f32x4 b0 = *(const f32x4*)(bsrc + gdx * 8);
      f32x4 b1 = *(const f32x4*)(bsrc + gdx * 8 + 4);
      *(short8*)(bdst + gdx * 8) = pack8(b0, b1);
    }
    __syncthreads();
    #pragma unroll
    for (int ks = 0; ks < 4; ++ks) {
      short8 af[4], bfr[4];
      #pragma unroll
      for (int i = 0; i < 4; ++i)
        af[i] = *(const short8*)(Al + (mh + i * 16 + fr) * 136 + ks * 32 + fq * 8);
      #pragma unroll
      for (int j = 0; j < 4; ++j)
        bfr[j] = *(const short8*)(Bl + (nh + j * 16 + fr) * 136 + ks * 32 + fq * 8);
      #pragma unroll
      for (int i = 0; i < 4; ++i)
        #pragma unroll
        for (int j = 0; j < 4; ++j)
          acc[i][j] = __builtin_amdgcn_mfma_f32_16x16x32_bf16(af[i], bfr[j], acc[i][j], 0, 0, 0);
    }
    __syncthreads();
  }

  // epilogue: sv = [gate 2*G2, r0..3][gate 2*G2+1, r0..3] for one unit
  const int G2 = nh >> 6;                 // gate-pair selector (lane bit3 in lstm)
  const int mh4 = mh >> 2;
  #pragma unroll
  for (int i = 0; i < 4; ++i) {
    const int s = s0 + mh4 + i * 4 + fq;
    #pragma unroll
    for (int nsub = 0; nsub < 2; ++nsub) {
      const int j0 = nsub, j1 = nsub + 2;
      const int cA = nh + j0 * 16 + fr, cB = nh + j1 * 16 + fr;
      const int u = u0 + nsub * 16 + fr;
      const int Q  = u >> 6;
      const int w2 = (u >> 3) & 7;
      const int lane = qb * 16 + G2 * 8 + (u & 7);
      short8 sv;
      #pragma unroll
      for (int r = 0; r < 4; ++r) {
        float vA = acc[i][j0][r] + biasl[cA];
        if (G2) vA *= 2.0f;                   // gate 2 pre-doubled (tanh form)
        float vB = acc[i][j1][r] + biasl[cB];
        sv[r]     = (short)f2bf(vA);
        sv[4 + r] = (short)f2bf(vB);
      }
      *(short8*)(xgf + ((size_t)((d * 4 + g) * 4 + Q) * 512 + s) * 4096
                     + (size_t)(w2 * 64 + lane) * 8) = sv;
    }
  }
}

// ---- one LSTM timestep; P = T&1 (compile-time) ----
template<int P>
__device__ __forceinline__ void lstm_step(
    int T, int d, int Q, int dg, int w, int l, int tid,
    const long long (&wreg)[2][8], float (&cst)[4],
    uint4& X, const u16* xsl,
    uint8_t* hboard, unsigned int* flags, u16* hhb)
{
  const int t_eff = d ? (511 - T) : T;
  const int q = l >> 4;
  const int RP = P ^ 1;  // parity holding h_{T-1}

  // 1. wait for the 3 partner quarters' h_{T-1}
  if (T > 0) {
    unsigned int* fl = flags + (size_t)dg * 2048 + (size_t)(T - 1) * 4;
    const int q1 = (Q + 1) & 3, q2 = (Q + 2) & 3, q3 = (Q + 3) & 3;
    while (__hip_atomic_load(fl + q1, __ATOMIC_RELAXED, __HIP_MEMORY_SCOPE_AGENT) == 0u ||
           __hip_atomic_load(fl + q2, __ATOMIC_RELAXED, __HIP_MEMORY_SCOPE_AGENT) == 0u ||
           __hip_atomic_load(fl + q3, __ATOMIC_RELAXED, __HIP_MEMORY_SCOPE_AGENT) == 0u)
      __builtin_amdgcn_s_sleep(1);
  }

  // 2. A-fragment chunk loads from h-board (L2, agent-scope)
  const unsigned long long* hbase =
      (const unsigned long long*)(hboard
        + ((size_t)(dg * 2 + RP) * 16 + (l & 15)) * 256 + (l >> 4) * 8);
  const int oA = (Q * 64) >> 3;
  const int oB = (((Q + 1) & 3) * 64) >> 3;
  const int oC = (((Q + 2) & 3) * 64) >> 3;
  const int oD = (((Q + 3) & 3) * 64) >> 3;
  long long a0 = (long long)__hip_atomic_load(hbase + oA,     __ATOMIC_RELAXED, __HIP_MEMORY_SCOPE_AGENT);
  long long a1 = (long long)__hip_atomic_load(hbase + oA + 4, __ATOMIC_RELAXED, __HIP_MEMORY_SCOPE_AGENT);
  long long a2 = (long long)__hip_atomic_load(hbase + oB,     __ATOMIC_RELAXED, __HIP_MEMORY_SCOPE_AGENT);
  long long a3 = (long long)__hip_atomic_load(hbase + oB + 4, __ATOMIC_RELAXED, __HIP_MEMORY_SCOPE_AGENT);
  long long a4 = (long long)__hip_atomic_load(hbase + oC,     __ATOMIC_RELAXED, __HIP_MEMORY_SCOPE_AGENT);
  long long a5 = (long long)__hip_atomic_load(hbase + oC + 4, __ATOMIC_RELAXED, __HIP_MEMORY_SCOPE_AGENT);
  long long a6 = (long long)__hip_atomic_load(hbase + oD,     __ATOMIC_RELAXED, __HIP_MEMORY_SCOPE_AGENT);
  long long a7 = (long long)__hip_atomic_load(hbase + oD + 4, __ATOMIC_RELAXED, __HIP_MEMORY_SCOPE_AGENT);

  // 3. EARLY xg prefetch for T+2 into a temp (lands during MFMA+gates)
  int tn = T + 2; if (tn > 511) tn = 511;
  const int sn = d ? (511 - tn) : tn;
  const uint4 TMP = *(const uint4*)(xsl + (size_t)sn * 4096);

  // 4. MFMA: 2 tiles x 8 K-chunks
  f32x4 c0 = {0.f,0.f,0.f,0.f}, c1 = {0.f,0.f,0.f,0.f};
#define MS(A, S) \
  c0 = __builtin_amdgcn_mfma_f32_16x16x32_fp8_fp8(A, wreg[0][S], c0, 0,0,0); \
  c1 = __builtin_amdgcn_mfma_f32_16x16x32_fp8_fp8(A, wreg[1][S], c1, 0,0,0);
  MS(a0,0) MS(a1,1) MS(a2,2) MS(a3,3) MS(a4,4) MS(a5,5) MS(a6,6) MS(a7,7)
#undef MS

  // 5. gate math; lane holds gates {2*b3, 2*b3+1} for unit u, 4 batches
  const u16* xcu = (const u16*)&X;
  const float S1 = 1.0f / 256.0f;
  const float St0 = (l & 8) ? (2.0f / 256.0f) : S1;   // t2=0 of b3 lanes = gate 2
  uint32_t pkv[4], bhv[4];
  #pragma unroll
  for (int r = 0; r < 4; ++r) {
    const float v0 = fmaf(c0[r], St0, bf2f(xcu[r]));
    const float v1 = fmaf(c1[r], S1,  bf2f(xcu[4 + r]));
    const float p0 = __shfl_xor(v0, 8, 64);
    const float p1 = __shfl_xor(v1, 8, 64);
    const bool b3 = (l & 8) != 0;
    const float iv = b3 ? p0 : v0;
    const float fv = b3 ? p1 : v1;
    const float gv = b3 ? v0 : p0;   // pre-doubled
    const float ov = b3 ? v1 : p1;
    const float si = __builtin_amdgcn_rcpf(1.0f + __expf(-iv));
    const float sf = __builtin_amdgcn_rcpf(1.0f + __expf(-fv));
    const float so = __builtin_amdgcn_rcpf(1.0f + __expf(-ov));
    const float tg = 1.0f - 2.0f * __builtin_amdgcn_rcpf(1.0f + __expf(gv));
    const float c  = sf * cst[r] + si * tg;
    cst[r] = c;
    const float th = 1.0f - 2.0f * __builtin_amdgcn_rcpf(1.0f + __expf(2.0f * c));
    const float hv = so * th;
    // fp8 publish pack (units u..u+3 gathered to lanes l%4==0)
    const float hsc = hv * 16.0f;
    const float o1 = __shfl_xor(hsc, 1, 64);
    const int pk = __builtin_amdgcn_cvt_pk_fp8_f32(hsc, o1, 0, false);
    const uint32_t lo = (uint32_t)(pk & 0xffff);
    const uint32_t hi = __shfl_xor(lo, 2, 64);
    pkv[r] = lo | (hi << 16);
    // bf16 history pack (units u,u+1 at lanes l%2==0)
    const float hn = __shfl_xor(hv, 1, 64);
    bhv[r] = (uint32_t)f2bf(hv) | ((uint32_t)f2bf(hn) << 16);
  }

  // 6. publish h_T to h-board (parity P)
  const int u = Q * 64 + w * 8 + (l & 7);
  if ((l & 0xB) == 0) {     // l%4==0 && !b3  (dedupe 2x gate redundancy)
    uint8_t* hw = hboard + ((size_t)(dg * 2 + P) * 16 + q * 4) * 256 + u;
    #pragma unroll
    for (int r = 0; r < 4; ++r)
      __hip_atomic_store((uint32_t*)(hw + (size_t)r * 256), pkv[r],
                         __ATOMIC_RELAXED, __HIP_MEMORY_SCOPE_AGENT);
  }

  __syncthreads();          // drains all waves' hboard stores
  if (tid == 0)
    __hip_atomic_store(flags + (size_t)dg * 2048 + (size_t)T * 4 + Q, 1u,
                       __ATOMIC_RELAXED, __HIP_MEMORY_SCOPE_AGENT);

  // 7. fire-and-forget bf16 history (drains at NEXT barrier, off critical path)
  if ((l & 9) == 0) {       // l%2==0 && !b3
    #pragma unroll
    for (int r = 0; r < 4; ++r)
      *(uint32_t*)(hhb + (size_t)r * 512 * 256 + (size_t)t_eff * 256) = bhv[r];
  }

  X = TMP;                  // commit prefetch into the parity register
}

// ---- BiLSTM recurrence: 32 WGs = quarter(4) x dir(2) x group(4) ----
// bid = Q*8 + dg -> all 4 quarters of a (d,g) share bid%8 (same XCD heuristic)
__global__ void __launch_bounds__(512, 2) lstm_kernel(
    const u16* __restrict__ xgf, const uint8_t* __restrict__ wfrag,
    u16* __restrict__ hhist, uint8_t* hboard, unsigned int* flags)
{
  const int tid = threadIdx.x;
  const int bid = blockIdx.x;          // 0..31
  const int Q = bid >> 3, dg = bid & 7;
  const int d = dg >> 2, g = dg & 3;
  const int w = tid >> 6, l = tid & 63;
  const int q = l >> 4;

  // register-resident fp8 weight fragments: 2 tiles x 8 kc = 32 VGPRs
  long long wreg[2][8];
  {
    const uint8_t* wb = wfrag + ((size_t)((d * 4 + Q) * 8 + w) * 2) * 8 * 64 * 8;
    #pragma unroll
    for (int t2 = 0; t2 < 2; ++t2)
      #pragma unroll
      for (int s = 0; s < 8; ++s)
        wreg[t2][s] = *(const long long*)(wb + ((size_t)(t2 * 8 + s) * 64 + l) * 8);
  }

  const u16* xsl = xgf + ((size_t)((d * 4 + g) * 4 + Q) * 512) * 4096 + (size_t)tid * 8;
  u16* hhb = hhist + ((size_t)(d * 64 + g * 16 + q * 4) * 512) * 256
                   + (Q * 64 + w * 8 + (l & 7));
  float cst[4] = {0.f, 0.f, 0.f, 0.f};

  uint4 xA = *(const uint4*)(xsl + (size_t)(d ? 511 : 0) * 4096);
  uint4 xB = *(const uint4*)(xsl + (size_t)(d ? 510 : 1) * 4096);

  for (int tt = 0; tt < 512; tt += 2) {
    lstm_step<0>(tt,     d, Q, dg, w, l, tid, wreg, cst, xA, xsl, hboard, flags, hhb);
    lstm_step<1>(tt + 1, d, Q, dg, w, l, tid, wreg, cst, xB, xsl, hboard, flags, hhb);
  }
}

// ---- feats = [hf|hb] @ w_out^T + b_out ----
__global__ void __launch_bounds__(256) proj_kernel(
    const u16* __restrict__ hhist, const float* __restrict__ w_out,
    const float* __restrict__ b_out, float* __restrict__ feats)
{
  __shared__ float wsm[9 * 512];
  __shared__ float bsm[9];
  const int tid = threadIdx.x;
  for (int i = tid; i < 4608; i += 256) wsm[i] = w_out[i];
  if (tid < 9) bsm[tid] = b_out[tid];
  __syncthreads();

  const int wv = tid >> 6, l = tid & 63;
  const int gw = blockIdx.x * 4 + wv;
  const int jb = l * 8;
  const int dd = jb >> 8;
  const int jloc = jb & 255;

  for (int qq = 0; qq < 8; ++qq) {
    const int pos = gw * 8 + qq;
    const int b = pos >> 9, s = pos & 511;
    const u16* hp = hhist + ((size_t)(dd * 64 + b) * 512 + s) * 256 + jloc;
    short8 hv8 = *(const short8*)hp;
    float hf[8];
    #pragma unroll
    for (int j = 0; j < 8; ++j) hf[j] = bf2f((u16)hv8[j]);
    float pt[9];
    #pragma unroll
    for (int tg2 = 0; tg2 < 9; ++tg2) {
      const float* wr = wsm + tg2 * 512 + jb;
      float a = 0.f;
      #pragma unroll
      for (int j = 0; j < 8; ++j) a = fmaf(hf[j], wr[j], a);
      pt[tg2] = a;
    }
    #pragma unroll
    for (int tg2 = 0; tg2 < 9; ++tg2)
      #pragma unroll
      for (int off = 32; off; off >>= 1)
        pt[tg2] += __shfl_xor(pt[tg2], off, 64);
    if (l == 0) {
      float* fo = feats + (size_t)pos * 9;
      #pragma unroll
      for (int tg2 = 0; tg2 < 9; ++tg2) fo[tg2] = pt[tg2] + bsm[tg2];
    }
  }
}

// ---- CRF NLL ----
__global__ void __launch_bounds__(64) crf_kernel(
    const float* __restrict__ feats, const int* __restrict__ tags,
    const float* __restrict__ strans, const float* __restrict__ etrans,
    const float* __restrict__ trans, float* out)
{
  __shared__ float em[512 * 9];
  __shared__ float tr[81];
  __shared__ int   tg[512];
  const int b = blockIdx.x, l = threadIdx.x;
  const float* fb = feats + (size_t)b * 512 * 9;
  for (int i = l; i < 4608; i += 64) em[i] = fb[i];
  for (int i = l; i < 512; i += 64) tg[i] = tags[b * 512 + i];
  if (l < 81) tr[l] = trans[l];
  __syncthreads();

  float sc = 0.f;
  for (int s = 1 + l; s < 512; s += 64)
    sc += tr[tg[s - 1] * 9 + tg[s]] + em[s * 9 + tg[s]];
  #pragma unroll
  for (int off = 32; off; off >>= 1) sc += __shfl_xor(sc, off, 64);
  const float score = sc + strans[tg[0]] + em[tg[0]] + etrans[tg[511]];

  const int jj = (l < 9) ? l : 0;
  float al = (l < 9) ? (strans[l] + em[l]) : -1e30f;
  for (int t = 1; t < 512; ++t) {
    float ai[9];
    #pragma unroll
    for (int i = 0; i < 9; ++i) ai[i] = __shfl(al, i, 64);
    float m = ai[0];
    #pragma unroll
    for (int i = 1; i < 9; ++i) m = fmaxf(m, ai[i]);
    float ssum = 0.f;
    #pragma unroll
    for (int i = 0; i < 9; ++i) ssum += __expf(ai[i] + tr[i * 9 + jj] - m);
    al = em[t * 9 + jj] + m + __logf(ssum);
  }
  float v = (l < 9) ? (al + etrans[l]) : -3.0e38f;
  float m2 = v;
  #pragma unroll
  for (int off = 32; off; off >>= 1) m2 = fmaxf(m2, __shfl_xor(m2, off, 64));
  float ex = (l < 9) ? __expf(v - m2) : 0.f;
  #pragma unroll
  for (int off = 32; off; off >>= 1) ex += __shfl_xor(ex, off, 64);
  const float logZ = m2 + __logf(ex);
  if (l == 0) atomicAdd(out, -(score - logZ) * (1.0f / 64.0f));
}

extern "C" void kernel_launch(void* const* d_in, const int* in_sizes, int n_in,
                              void* d_out, int out_size, void* d_ws, size_t ws_size,
                              hipStream_t stream) {
  (void)in_sizes; (void)n_in; (void)out_size; (void)ws_size;
  const int*   sent = (const int*)d_in[0];
  const int*   tags = (const int*)d_in[1];
  const float* emb  = (const float*)d_in[3];
  const float* wihf = (const float*)d_in[4];
  const float* whhf = (const float*)d_in[5];
  const float* bihf = (const float*)d_in[6];
  const float* bhhf = (const float*)d_in[7];
  const float* wihb = (const float*)d_in[8];
  const float* whhb = (const float*)d_in[9];
  const float* bihb = (const float*)d_in[10];
  const float* bhhb = (const float*)d_in[11];
  const float* wout = (const float*)d_in[12];
  const float* bout = (const float*)d_in[13];
  const float* strn = (const float*)d_in[14];
  const float* etrn = (const float*)d_in[15];
  const float* trn  = (const float*)d_in[16];

  char* ws = (char*)d_ws;
  unsigned int* flags = (unsigned int*)(ws + OFF_FLAGS);
  uint8_t* hboard = (uint8_t*)(ws + OFF_HBOARD);
  float*   biasb = (float*)(ws + OFF_BIAS);
  uint8_t* wfrag = (uint8_t*)(ws + OFF_WFRAG);
  u16*     hhist = (u16*)(ws + OFF_HHIST);
  float*   feats = (float*)(ws + OFF_FEATS);
  u16*     xgf   = (u16*)(ws + OFF_XG);
  float*   out   = (float*)d_out;

  hipMemsetAsync(ws, 0, 131072, stream);              // flags + hboard
  hipMemsetAsync(d_out, 0, sizeof(float), stream);

  hipFuncSetAttribute(reinterpret_cast<const void*>(xg_gemm_kernel),
                      hipFuncAttributeMaxDynamicSharedMemorySize, 70656);

  bias_kernel<<<8, 256, 0, stream>>>(bihf, bhhf, bihb, bhhb, biasb);
  wfrag_prep_kernel<<<256, 256, 0, stream>>>(whhf, whhb, wfrag);
  xg_gemm_kernel<<<dim3(16, 256), 256, 70656, stream>>>(sent, emb, wihf, wihb, biasb, xgf);
  lstm_kernel<<<32, 512, 0, stream>>>(xgf, wfrag, hhist, hboard, flags);
  proj_kernel<<<1024, 256, 0, stream>>>(hhist, wout, bout, feats);
  crf_kernel<<<64, 64, 0, stream>>>(feats, tags, strn, etrn, trn, out);
}

// Round 8
// 1668.544 us; speedup vs baseline: 1.2636x; 1.2636x over previous
//
#include <hip/hip_runtime.h>
#include <stdint.h>

// BiLSTM-CRF forward on MI355X.
// R8: R6 skeleton + (a) xg prefetch issued at TOP of step (no barrier drain),
//     (b) flag poll deferred until after own-half MFMAs, (c) hhist stores
//     moved after the barrier. No other changes.
typedef unsigned short u16;
typedef __attribute__((ext_vector_type(4))) float f32x4;
typedef __attribute__((ext_vector_type(8))) short short8;

#define OFF_FLAGS  ((size_t)0)           // [16][512] u32 = 32 KB
#define OFF_INBOX  ((size_t)32768)       // [16][2][16][128] fp8 = 64 KB
#define OFF_BIAS   ((size_t)98304)       // 2048*4
#define OFF_WFRAG  ((size_t)131072)      // 2*2*8*4*8*64*8 = 512 KB fp8 w_hh frags
#define OFF_HHIST  ((size_t)1048576)     // [2][64][512][256] u16 = 32 MB
#define OFF_FEATS  ((size_t)34603008)    // 32768*9*4
#define OFF_XG     ((size_t)37748736)    // [2*4][512][1024 threads][16] u16 = 128 MB

__device__ __forceinline__ u16 f2bf(float f) {
  union { float f; uint32_t u; } v; v.f = f;
  uint32_t u = v.u;
  return (u16)((u + 0x7fffu + ((u >> 16) & 1u)) >> 16);
}
__device__ __forceinline__ float bf2f(u16 h) {
  union { uint32_t u; float f; } v; v.u = ((uint32_t)h) << 16; return v.f;
}
__device__ __forceinline__ float bfh(uint32_t wrd, int hh) {
  return bf2f((u16)(wrd >> (16 * hh)));
}
__device__ __forceinline__ short8 pack8(f32x4 a, f32x4 b) {
  short8 r;
  r[0] = (short)f2bf(a[0]); r[1] = (short)f2bf(a[1]);
  r[2] = (short)f2bf(a[2]); r[3] = (short)f2bf(a[3]);
  r[4] = (short)f2bf(b[0]); r[5] = (short)f2bf(b[1]);
  r[6] = (short)f2bf(b[2]); r[7] = (short)f2bf(b[3]);
  return r;
}

// ---- combined input-gate bias ----
__global__ void bias_kernel(const float* __restrict__ bihf, const float* __restrict__ bhhf,
                            const float* __restrict__ bihb, const float* __restrict__ bhhb,
                            float* __restrict__ bias) {
  int n = blockIdx.x * 256 + threadIdx.x;
  if (n < 1024) bias[n] = bihf[n] + bhhf[n];
  else          bias[n] = bihb[n - 1024] + bhhb[n - 1024];
}

// ---- w_hh -> fp8 e4m3 B-fragments (x16 scale) ----
// K-chunk slots: 0..3 = OWN half units, 4..7 = PARTNER half units.
__global__ void wfrag_prep_kernel(const float* __restrict__ whhf,
                                  const float* __restrict__ whhb,
                                  uint8_t* __restrict__ wfrag) {
  int gid = blockIdx.x * 256 + threadIdx.x;   // 0..65535
  const int l    = gid & 63;
  const int kt   = (gid >> 6) & 7;
  const int gate = (gid >> 9) & 3;
  const int w    = (gid >> 11) & 7;
  const int half = (gid >> 14) & 1;
  const int d    = (gid >> 15) & 1;
  const float* W = d ? whhb : whhf;
  const int row = gate * 256 + half * 128 + w * 16 + (l & 15);
  const int khalf = (kt < 4) ? half : (1 - half);
  const int k0  = khalf * 128 + (kt & 3) * 32 + (l >> 4) * 8;
  uint32_t out[2] = {0u, 0u};
  #pragma unroll
  for (int jj = 0; jj < 4; ++jj) {
    const float f0 = W[(size_t)row * 256 + k0 + jj * 2]     * 16.0f;
    const float f1 = W[(size_t)row * 256 + k0 + jj * 2 + 1] * 16.0f;
    const int pk = __builtin_amdgcn_cvt_pk_fp8_f32(f0, f1, 0, false);
    out[jj >> 1] |= (uint32_t)(pk & 0xffff) << (16 * (jj & 1));
  }
  *(uint2*)(wfrag + (size_t)gid * 8) = make_uint2(out[0], out[1]);
}

// ---- xg = gather(emb) @ w_ih^T + bias, coalesced lstm-order epilogue ----
__global__ void __launch_bounds__(256) xg_gemm_kernel(
    const int* __restrict__ sent, const float* __restrict__ emb,
    const float* __restrict__ w_ih_f, const float* __restrict__ w_ih_b,
    const float* __restrict__ bias, u16* __restrict__ xgf)
{
  extern __shared__ char smem[];
  u16*   Al    = (u16*)smem;             // [128][136]
  u16*   Bl    = (u16*)(smem + 34816);   // [128][136]
  float* biasl = (float*)(smem + 69632); // [128]
  int*   tokl  = (int*)(smem + 70144);   // [128]

  const int tid = threadIdx.x;
  const int d  = blockIdx.x >> 3, u0 = (blockIdx.x & 7) * 32;
  const int g  = blockIdx.y >> 6, qb = (blockIdx.y >> 4) & 3, s0 = (blockIdx.y & 15) * 32;
  const float* wih = d ? w_ih_b : w_ih_f;

  if (tid < 128) {
    tokl[tid]  = sent[(size_t)(g * 16 + qb * 4 + (tid & 3)) * 512 + s0 + (tid >> 2)];
    biasl[tid] = bias[d * 1024 + (tid >> 5) * 256 + u0 + (tid & 31)];
  }
  __syncthreads();

  f32x4 acc[4][4];
  #pragma unroll
  for (int i = 0; i < 4; ++i)
    #pragma unroll
    for (int j = 0; j < 4; ++j) acc[i][j] = (f32x4){0.f, 0.f, 0.f, 0.f};

  const int wv = tid >> 6, l = tid & 63;
  const int mh = (wv >> 1) * 64, nh = (wv & 1) * 64;
  const int fr = l & 15, fq = l >> 4;
  const int rr = tid >> 1, c0 = (tid & 1) * 64;

  for (int kc = 0; kc < 2; ++kc) {
    const int k0 = kc * 128;
    const float* asrc = emb + (size_t)tokl[rr] * 256 + k0 + c0;
    const float* bsrc = wih + (size_t)((rr >> 5) * 256 + u0 + (rr & 31)) * 256 + k0 + c0;
    u16* adst = Al + rr * 136 + c0;
    u16* bdst = Bl + rr * 136 + c0;
    #pragma unroll
    for (int gdx = 0; gdx < 8; ++gdx) {
      f32x4 a0 = *(const f32x4*)(asrc + gdx * 8);
      f32x4 a1 = *(const f32x4*)(asrc + gdx * 8 + 4);
      *(short8*)(adst + gdx * 8) = pack8(a0, a1);
      f32x4 b0 = *(const f32x4*)(bsrc + gdx * 8);
      f32x4 b1 = *(const f32x4*)(bsrc + gdx * 8 + 4);
      *(short8*)(bdst + gdx * 8) = pack8(b0, b1);
    }
    __syncthreads();
    #pragma unroll
    for (int ks = 0; ks < 4; ++ks) {
      short8 af[4], bfr[4];
      #pragma unroll
      for (int i = 0; i < 4; ++i)
        af[i] = *(const short8*)(Al + (mh + i * 16 + fr) * 136 + ks * 32 + fq * 8);
      #pragma unroll
      for (int j = 0; j < 4; ++j)
        bfr[j] = *(const short8*)(Bl + (nh + j * 16 + fr) * 136 + ks * 32 + fq * 8);
      #pragma unroll
      for (int i = 0; i < 4; ++i)
        #pragma unroll
        for (int j = 0; j < 4; ++j)
          acc[i][j] = __builtin_amdgcn_mfma_f32_16x16x32_bf16(af[i], bfr[j], acc[i][j], 0, 0, 0);
    }
    __syncthreads();
  }

  const int g0 = nh >> 5;
  const int mh4 = mh >> 2;
  u16* xbase = xgf + ((size_t)(d * 4 + g) * 512) * 16384;
  #pragma unroll
  for (int i = 0; i < 4; ++i) {
    const int s = s0 + mh4 + i * 4 + fq;
    #pragma unroll
    for (int nsub = 0; nsub < 2; ++nsub) {
      const int j0 = nsub, j1 = nsub + 2;
      const int cA = nh + j0 * 16 + fr, cB = nh + j1 * 16 + fr;
      const int u = u0 + nsub * 16 + fr;
      const int wl = (u & 127) >> 4, hf_ = u >> 7;
      const int tp = hf_ * 512 + wl * 64 + qb * 16 + (u & 15);
      short8 sv;
      #pragma unroll
      for (int r = 0; r < 4; ++r) {
        float vA = acc[i][j0][r] + biasl[cA];
        if (g0 == 2) vA *= 2.0f;
        float vB = acc[i][j1][r] + biasl[cB];
        sv[r]     = (short)f2bf(vA);
        sv[4 + r] = (short)f2bf(vB);
      }
      *(short8*)(xbase + (size_t)s * 16384 + tp * 16 + g0 * 4) = sv;
    }
  }
}

// ---- one LSTM timestep; CB/PW are compile-time parities ----
template<int CB, int PW>
__device__ __forceinline__ void lstm_step(
    int T, int d, int n, int q, int w, int tid,
    const long long (&wreg)[4][8], float (&cst)[4],
    uint4& X0, uint4& X1,
    uint8_t (*hx)[16][136],
    const unsigned int* myflag, unsigned int* toflag,
    const uint8_t* myinbox, uint8_t* toinbox,
    const u16* xsl, u16* hhb)
{
  const int t_eff = d ? (511 - T) : T;

  // (a) EARLY xg prefetch for T+2 — has the whole step to land before use,
  //     and its vmcnt is drained by work, not by the barrier.
  int tn = T + 2; if (tn > 511) tn = 511;
  const int sn = d ? (511 - tn) : tn;
  const uint4* pfp = (const uint4*)(xsl + (size_t)sn * 16384);
  const uint4 T0 = pfp[0];
  const uint4 T1 = pfp[1];

  // own A-frags from LDS (slots 0..3)
  long long a0, a1, a2, a3, a4, a5, a6, a7;
  {
    const uint8_t* hr = &hx[CB][n][q * 8];
    a0 = *(const long long*)(hr + 0);
    a1 = *(const long long*)(hr + 32);
    a2 = *(const long long*)(hr + 64);
    a3 = *(const long long*)(hr + 96);
  }

  // own-half MFMAs first (hides partner flag/inbox latency)
  f32x4 c0 = {0.f,0.f,0.f,0.f}, c1 = {0.f,0.f,0.f,0.f};
  f32x4 c2 = {0.f,0.f,0.f,0.f}, c3 = {0.f,0.f,0.f,0.f};
#define OWN_MFMA(ACC, G) \
  ACC = __builtin_amdgcn_mfma_f32_16x16x32_fp8_fp8(a0, wreg[G][0], ACC, 0,0,0); \
  ACC = __builtin_amdgcn_mfma_f32_16x16x32_fp8_fp8(a1, wreg[G][1], ACC, 0,0,0); \
  ACC = __builtin_amdgcn_mfma_f32_16x16x32_fp8_fp8(a2, wreg[G][2], ACC, 0,0,0); \
  ACC = __builtin_amdgcn_mfma_f32_16x16x32_fp8_fp8(a3, wreg[G][3], ACC, 0,0,0);
  OWN_MFMA(c0, 0) OWN_MFMA(c1, 1) OWN_MFMA(c2, 2) OWN_MFMA(c3, 3)
#undef OWN_MFMA

  // (b) deferred poll + remote loads (slots 4..7)
  if (T > 0) {
    while (__hip_atomic_load(myflag + (T - 1), __ATOMIC_RELAXED, __HIP_MEMORY_SCOPE_AGENT) == 0u)
      __builtin_amdgcn_s_sleep(1);
    const unsigned long long* rb =
        (const unsigned long long*)(myinbox + (size_t)CB * 2048) + (n * 16 + q);
    a4 = (long long)__hip_atomic_load(rb + 0,  __ATOMIC_RELAXED, __HIP_MEMORY_SCOPE_AGENT);
    a5 = (long long)__hip_atomic_load(rb + 4,  __ATOMIC_RELAXED, __HIP_MEMORY_SCOPE_AGENT);
    a6 = (long long)__hip_atomic_load(rb + 8,  __ATOMIC_RELAXED, __HIP_MEMORY_SCOPE_AGENT);
    a7 = (long long)__hip_atomic_load(rb + 12, __ATOMIC_RELAXED, __HIP_MEMORY_SCOPE_AGENT);
  } else {
    a4 = a5 = a6 = a7 = 0ll;
  }

#define REM_MFMA(ACC, G) \
  ACC = __builtin_amdgcn_mfma_f32_16x16x32_fp8_fp8(a4, wreg[G][4], ACC, 0,0,0); \
  ACC = __builtin_amdgcn_mfma_f32_16x16x32_fp8_fp8(a5, wreg[G][5], ACC, 0,0,0); \
  ACC = __builtin_amdgcn_mfma_f32_16x16x32_fp8_fp8(a6, wreg[G][6], ACC, 0,0,0); \
  ACC = __builtin_amdgcn_mfma_f32_16x16x32_fp8_fp8(a7, wreg[G][7], ACC, 0,0,0);
  REM_MFMA(c0, 0) REM_MFMA(c1, 1) REM_MFMA(c2, 2) REM_MFMA(c3, 3)
#undef REM_MFMA

  const float S1 = 1.0f / 256.0f;
  const float S2 = 2.0f / 256.0f;
  float hs[4];
  uint32_t hist[4];
  #pragma unroll
  for (int r = 0; r < 4; ++r) {
    const uint32_t wi = (r < 2) ? X0.x : X0.y;
    const uint32_t wf = (r < 2) ? X0.z : X0.w;
    const uint32_t wg = (r < 2) ? X1.x : X1.y;
    const uint32_t wo = (r < 2) ? X1.z : X1.w;
    const int hp = r & 1;
    const float iv = fmaf(c0[r], S1, bfh(wi, hp));
    const float fv = fmaf(c1[r], S1, bfh(wf, hp));
    const float gv = fmaf(c2[r], S2, bfh(wg, hp));
    const float ov = fmaf(c3[r], S1, bfh(wo, hp));
    const float si = __builtin_amdgcn_rcpf(1.0f + __expf(-iv));
    const float sf = __builtin_amdgcn_rcpf(1.0f + __expf(-fv));
    const float so = __builtin_amdgcn_rcpf(1.0f + __expf(-ov));
    const float tg = 1.0f - 2.0f * __builtin_amdgcn_rcpf(1.0f + __expf(gv));
    const float c  = sf * cst[r] + si * tg;
    cst[r] = c;
    const float th = 1.0f - 2.0f * __builtin_amdgcn_rcpf(1.0f + __expf(2.0f * c));
    const float hv = so * th;
    hs[r] = hv * 16.0f;
    hist[r] = (uint32_t)f2bf(hv);
  }

  // pack fp8 x4 (units n..n+3) and publish: own LDS + partner inbox
  #pragma unroll
  for (int r = 0; r < 4; ++r) {
    const float o1 = __shfl_xor(hs[r], 1, 64);
    const int pk = __builtin_amdgcn_cvt_pk_fp8_f32(hs[r], o1, 0, false);
    const uint32_t lo = (uint32_t)(pk & 0xffff);
    const uint32_t hi = __shfl_xor(lo, 2, 64);
    if ((n & 3) == 0) {
      const uint32_t pv = lo | (hi << 16);
      *(uint32_t*)&hx[PW][q * 4 + r][w * 16 + n] = pv;
      __hip_atomic_store((uint32_t*)(toinbox + (size_t)PW * 2048 + (q * 4 + r) * 128 + w * 16 + n),
                         pv, __ATOMIC_RELAXED, __HIP_MEMORY_SCOPE_AGENT);
    }
  }

  __syncthreads();   // drains inbox stores (prefetch already landed under MFMAs)
  if (tid == 0)
    __hip_atomic_store(toflag + T, 1u, __ATOMIC_RELAXED, __HIP_MEMORY_SCOPE_AGENT);

  // (c) hhist stores AFTER the barrier — drain during the next step
  {
    u16* hh = hhb + (size_t)t_eff * 256;
    #pragma unroll
    for (int r = 0; r < 4; ++r)
      hh[(size_t)r * 512 * 256] = (u16)hist[r];
  }

  X0 = T0; X1 = T1;
}

// ---- BiLSTM recurrence: 16 WGs = half(2) x dir(2) x group(4 of 16 batches) ----
__global__ void __launch_bounds__(512, 2) lstm_kernel(
    const u16* __restrict__ xgf, const uint8_t* __restrict__ wfrag,
    u16* __restrict__ hhist, uint8_t* inbox, unsigned int* flags)
{
  __shared__ uint8_t hx[2][16][136];

  const int tid = threadIdx.x;
  const int bid = blockIdx.x;          // 0..15
  const int half = bid >> 3, dg = bid & 7;
  const int d = dg >> 2, g = dg & 3;
  const int w = tid >> 6, l = tid & 63;
  const int q = l >> 4, n = l & 15;

  long long wreg[4][8];
  {
    const uint8_t* wb = wfrag + (size_t)(((d * 2 + half) * 8 + w) * 4 * 8 * 64) * 8;
    #pragma unroll
    for (int gate = 0; gate < 4; ++gate)
      #pragma unroll
      for (int kt = 0; kt < 8; ++kt)
        wreg[gate][kt] = *(const long long*)(wb + ((size_t)(gate * 8 + kt) * 64 + l) * 8);
  }

  for (int i = tid; i < 1088; i += 512) ((uint32_t*)hx)[i] = 0u;   // h_{-1}=0

  const uint8_t* myinbox = inbox + (size_t)bid * 4096;
  uint8_t* toinbox = inbox + (size_t)(bid ^ 8) * 4096;
  const unsigned int* myflag = flags + (size_t)bid * 512;
  unsigned int* toflag = flags + (size_t)(bid ^ 8) * 512;

  const u16* xsl = xgf + ((size_t)(d * 4 + g) * 512) * 16384 + (size_t)(half * 512 + tid) * 16;
  float cst[4] = {0.f, 0.f, 0.f, 0.f};
  u16* hhb = hhist + ((size_t)(d * 64 + g * 16 + q * 4) * 512) * 256 + (half * 128 + w * 16 + n);

  uint4 xA0, xA1, xB0, xB1;
  {
    const uint4* p0 = (const uint4*)(xsl + (size_t)(d ? 511 : 0) * 16384);
    xA0 = p0[0]; xA1 = p0[1];
    const uint4* p1 = (const uint4*)(xsl + (size_t)(d ? 510 : 1) * 16384);
    xB0 = p1[0]; xB1 = p1[1];
  }
  __syncthreads();

  for (int tt = 0; tt < 512; tt += 2) {
    lstm_step<1, 0>(tt,     d, n, q, w, tid, wreg, cst, xA0, xA1, hx,
                    myflag, toflag, myinbox, toinbox, xsl, hhb);
    lstm_step<0, 1>(tt + 1, d, n, q, w, tid, wreg, cst, xB0, xB1, hx,
                    myflag, toflag, myinbox, toinbox, xsl, hhb);
  }
}

// ---- feats = [hf|hb] @ w_out^T + b_out ----
__global__ void __launch_bounds__(256) proj_kernel(
    const u16* __restrict__ hhist, const float* __restrict__ w_out,
    const float* __restrict__ b_out, float* __restrict__ feats)
{
  __shared__ float wsm[9 * 512];
  __shared__ float bsm[9];
  const int tid = threadIdx.x;
  for (int i = tid; i < 4608; i += 256) wsm[i] = w_out[i];
  if (tid < 9) bsm[tid] = b_out[tid];
  __syncthreads();

  const int wv = tid >> 6, l = tid & 63;
  const int gw = blockIdx.x * 4 + wv;
  const int jb = l * 8;
  const int dd = jb >> 8;
  const int jloc = jb & 255;

  for (int qq = 0; qq < 8; ++qq) {
    const int pos = gw * 8 + qq;
    const int b = pos >> 9, s = pos & 511;
    const u16* hp = hhist + ((size_t)(dd * 64 + b) * 512 + s) * 256 + jloc;
    short8 hv8 = *(const short8*)hp;
    float hf[8];
    #pragma unroll
    for (int j = 0; j < 8; ++j) hf[j] = bf2f((u16)hv8[j]);
    float pt[9];
    #pragma unroll
    for (int tg2 = 0; tg2 < 9; ++tg2) {
      const float* wr = wsm + tg2 * 512 + jb;
      float a = 0.f;
      #pragma unroll
      for (int j = 0; j < 8; ++j) a = fmaf(hf[j], wr[j], a);
      pt[tg2] = a;
    }
    #pragma unroll
    for (int tg2 = 0; tg2 < 9; ++tg2)
      #pragma unroll
      for (int off = 32; off; off >>= 1)
        pt[tg2] += __shfl_xor(pt[tg2], off, 64);
    if (l == 0) {
      float* fo = feats + (size_t)pos * 9;
      #pragma unroll
      for (int tg2 = 0; tg2 < 9; ++tg2) fo[tg2] = pt[tg2] + bsm[tg2];
    }
  }
}

// ---- CRF NLL ----
__global__ void __launch_bounds__(64) crf_kernel(
    const float* __restrict__ feats, const int* __restrict__ tags,
    const float* __restrict__ strans, const float* __restrict__ etrans,
    const float* __restrict__ trans, float* out)
{
  __shared__ float em[512 * 9];
  __shared__ float tr[81];
  __shared__ int   tg[512];
  const int b = blockIdx.x, l = threadIdx.x;
  const float* fb = feats + (size_t)b * 512 * 9;
  for (int i = l; i < 4608; i += 64) em[i] = fb[i];
  for (int i = l; i < 512; i += 64) tg[i] = tags[b * 512 + i];
  if (l < 81) tr[l] = trans[l];
  __syncthreads();

  float sc = 0.f;
  for (int s = 1 + l; s < 512; s += 64)
    sc += tr[tg[s - 1] * 9 + tg[s]] + em[s * 9 + tg[s]];
  #pragma unroll
  for (int off = 32; off; off >>= 1) sc += __shfl_xor(sc, off, 64);
  const float score = sc + strans[tg[0]] + em[tg[0]] + etrans[tg[511]];

  const int jj = (l < 9) ? l : 0;
  float al = (l < 9) ? (strans[l] + em[l]) : -1e30f;
  for (int t = 1; t < 512; ++t) {
    float ai[9];
    #pragma unroll
    for (int i = 0; i < 9; ++i) ai[i] = __shfl(al, i, 64);
    float m = ai[0];
    #pragma unroll
    for (int i = 1; i < 9; ++i) m = fmaxf(m, ai[i]);
    float ssum = 0.f;
    #pragma unroll
    for (int i = 0; i < 9; ++i) ssum += __expf(ai[i] + tr[i * 9 + jj] - m);
    al = em[t * 9 + jj] + m + __logf(ssum);
  }
  float v = (l < 9) ? (al + etrans[l]) : -3.0e38f;
  float m2 = v;
  #pragma unroll
  for (int off = 32; off; off >>= 1) m2 = fmaxf(m2, __shfl_xor(m2, off, 64));
  float ex = (l < 9) ? __expf(v - m2) : 0.f;
  #pragma unroll
  for (int off = 32; off; off >>= 1) ex += __shfl_xor(ex, off, 64);
  const float logZ = m2 + __logf(ex);
  if (l == 0) atomicAdd(out, -(score - logZ) * (1.0f / 64.0f));
}

extern "C" void kernel_launch(void* const* d_in, const int* in_sizes, int n_in,
                              void* d_out, int out_size, void* d_ws, size_t ws_size,
                              hipStream_t stream) {
  (void)in_sizes; (void)n_in; (void)out_size; (void)ws_size;
  const int*   sent = (const int*)d_in[0];
  const int*   tags = (const int*)d_in[1];
  const float* emb  = (const float*)d_in[3];
  const float* wihf = (const float*)d_in[4];
  const float* whhf = (const float*)d_in[5];
  const float* bihf = (const float*)d_in[6];
  const float* bhhf = (const float*)d_in[7];
  const float* wihb = (const float*)d_in[8];
  const float* whhb = (const float*)d_in[9];
  const float* bihb = (const float*)d_in[10];
  const float* bhhb = (const float*)d_in[11];
  const float* wout = (const float*)d_in[12];
  const float* bout = (const float*)d_in[13];
  const float* strn = (const float*)d_in[14];
  const float* etrn = (const float*)d_in[15];
  const float* trn  = (const float*)d_in[16];

  char* ws = (char*)d_ws;
  unsigned int* flags = (unsigned int*)(ws + OFF_FLAGS);
  uint8_t* inbox = (uint8_t*)(ws + OFF_INBOX);
  float*   biasb = (float*)(ws + OFF_BIAS);
  uint8_t* wfrag = (uint8_t*)(ws + OFF_WFRAG);
  u16*     hhist = (u16*)(ws + OFF_HHIST);
  float*   feats = (float*)(ws + OFF_FEATS);
  u16*     xgf   = (u16*)(ws + OFF_XG);
  float*   out   = (float*)d_out;

  hipMemsetAsync(ws, 0, 98304, stream);               // flags + inbox
  hipMemsetAsync(d_out, 0, sizeof(float), stream);

  hipFuncSetAttribute(reinterpret_cast<const void*>(xg_gemm_kernel),
                      hipFuncAttributeMaxDynamicSharedMemorySize, 70656);

  bias_kernel<<<8, 256, 0, stream>>>(bihf, bhhf, bihb, bhhb, biasb);
  wfrag_prep_kernel<<<256, 256, 0, stream>>>(whhf, whhb, wfrag);
  xg_gemm_kernel<<<dim3(16, 256), 256, 70656, stream>>>(sent, emb, wihf, wihb, biasb, xgf);
  lstm_kernel<<<16, 512, 0, stream>>>(xgf, wfrag, hhist, inbox, flags);
  proj_kernel<<<1024, 256, 0, stream>>>(hhist, wout, bout, feats);
  crf_kernel<<<64, 64, 0, stream>>>(feats, tags, strn, etrn, trn, out);
}

// Round 9
// 1633.162 us; speedup vs baseline: 1.2909x; 1.0217x over previous
//
#include <hip/hip_runtime.h>
#include <stdint.h>

// BiLSTM-CRF forward on MI355X.
// R9: self-contained 8-WG LSTM (R3 structure: full fp8 weights in regs/AGPRs,
//     LDS-only h exchange, 1 barrier/step, NO agent-scope ops in the loop)
//     + template-parity unroll (no spill) + top-of-step distance-2 xg prefetch
//     + post-barrier hhist stores + coalesced gemm epilogue in lstm lane order.
typedef unsigned short u16;
typedef __attribute__((ext_vector_type(4))) float f32x4;
typedef __attribute__((ext_vector_type(8))) short short8;

#define OFF_BIAS   ((size_t)0)           // 2048*4
#define OFF_WFRAG  ((size_t)8192)        // 2*8*2*4*8*64*8 = 512 KB fp8 w_hh frags
#define OFF_HHIST  ((size_t)1048576)     // [2][64][512][256] u16 = 32 MB
#define OFF_FEATS  ((size_t)34603008)    // 32768*9*4
#define OFF_XG     ((size_t)37748736)    // [2*4][512 s][512 tid][32 u16] = 128 MB

__device__ __forceinline__ u16 f2bf(float f) {
  union { float f; uint32_t u; } v; v.f = f;
  uint32_t u = v.u;
  return (u16)((u + 0x7fffu + ((u >> 16) & 1u)) >> 16);
}
__device__ __forceinline__ float bf2f(u16 h) {
  union { uint32_t u; float f; } v; v.u = ((uint32_t)h) << 16; return v.f;
}
__device__ __forceinline__ float bfh(uint32_t wrd, int hh) {
  return bf2f((u16)(wrd >> (16 * hh)));
}
__device__ __forceinline__ short8 pack8(f32x4 a, f32x4 b) {
  short8 r;
  r[0] = (short)f2bf(a[0]); r[1] = (short)f2bf(a[1]);
  r[2] = (short)f2bf(a[2]); r[3] = (short)f2bf(a[3]);
  r[4] = (short)f2bf(b[0]); r[5] = (short)f2bf(b[1]);
  r[6] = (short)f2bf(b[2]); r[7] = (short)f2bf(b[3]);
  return r;
}

// ---- combined input-gate bias ----
__global__ void bias_kernel(const float* __restrict__ bihf, const float* __restrict__ bhhf,
                            const float* __restrict__ bihb, const float* __restrict__ bhhb,
                            float* __restrict__ bias) {
  int n = blockIdx.x * 256 + threadIdx.x;
  if (n < 1024) bias[n] = bihf[n] + bhhf[n];
  else          bias[n] = bihb[n - 1024] + bhhb[n - 1024];
}

// ---- w_hh -> fp8 e4m3 B-fragments (x16 scale), K-order permuted by pi ----
// pi: k = w*32 + n*2 + ubi  where unit u = w*32 + ubi*16 + n   (R3-verified)
// wfrag[(((((d*8+w)*2+ubi)*4+gate)*8+kt)*64+l)*8 + j]
// row = gate*256 + w*32 + ubi*16 + (l&15); k = kt*32 + (l>>4)*8 + j
__global__ void wfrag_prep_kernel(const float* __restrict__ whhf,
                                  const float* __restrict__ whhb,
                                  uint8_t* __restrict__ wfrag) {
  int gid = blockIdx.x * 256 + threadIdx.x;   // 0..32767
  const int l    = gid & 63;
  const int kt   = (gid >> 6) & 7;
  const int gate = (gid >> 9) & 3;
  const int ubi  = (gid >> 11) & 1;
  const int w    = (gid >> 12) & 7;
  const int d    = (gid >> 15) & 1;
  const float* W = d ? whhb : whhf;
  const int n = l & 15, q = l >> 4;
  const int row = gate * 256 + w * 32 + ubi * 16 + n;
  uint32_t out[2] = {0u, 0u};
  #pragma unroll
  for (int jj = 0; jj < 4; ++jj) {
    const int k0 = kt * 32 + q * 8 + jj * 2;
    const int k1 = k0 + 1;
    const int u0 = (k0 >> 5) * 32 + (k0 & 1) * 16 + ((k0 & 31) >> 1);
    const int u1 = (k1 >> 5) * 32 + (k1 & 1) * 16 + ((k1 & 31) >> 1);
    const float f0 = W[(size_t)row * 256 + u0] * 16.0f;
    const float f1 = W[(size_t)row * 256 + u1] * 16.0f;
    const int pk = __builtin_amdgcn_cvt_pk_fp8_f32(f0, f1, 0, false);
    out[jj >> 1] |= (uint32_t)(pk & 0xffff) << (16 * (jj & 1));
  }
  *(uint2*)(wfrag + (size_t)gid * 8) = make_uint2(out[0], out[1]);
}

// ---- xg = gather(emb) @ w_ih^T + bias, coalesced epilogue in lstm lane order ----
// Per lstm thread tid = w*64 + q*16 + n: 32 u16 = [ubi(2)][gate(4)][r(4)].
__global__ void __launch_bounds__(256) xg_gemm_kernel(
    const int* __restrict__ sent, const float* __restrict__ emb,
    const float* __restrict__ w_ih_f, const float* __restrict__ w_ih_b,
    const float* __restrict__ bias, u16* __restrict__ xgf)
{
  extern __shared__ char smem[];
  u16*   Al    = (u16*)smem;             // [128][136]
  u16*   Bl    = (u16*)(smem + 34816);   // [128][136]
  float* biasl = (float*)(smem + 69632); // [128]
  int*   tokl  = (int*)(smem + 70144);   // [128]

  const int tid = threadIdx.x;
  const int d  = blockIdx.x >> 3, u0 = (blockIdx.x & 7) * 32;
  const int g  = blockIdx.y >> 6, qb = (blockIdx.y >> 4) & 3, s0 = (blockIdx.y & 15) * 32;
  const float* wih = d ? w_ih_b : w_ih_f;

  if (tid < 128) {
    tokl[tid]  = sent[(size_t)(g * 16 + qb * 4 + (tid & 3)) * 512 + s0 + (tid >> 2)];
    biasl[tid] = bias[d * 1024 + (tid >> 5) * 256 + u0 + (tid & 31)];
  }
  __syncthreads();

  f32x4 acc[4][4];
  #pragma unroll
  for (int i = 0; i < 4; ++i)
    #pragma unroll
    for (int j = 0; j < 4; ++j) acc[i][j] = (f32x4){0.f, 0.f, 0.f, 0.f};

  const int wv = tid >> 6, l = tid & 63;
  const int mh = (wv >> 1) * 64, nh = (wv & 1) * 64;
  const int fr = l & 15, fq = l >> 4;
  const int rr = tid >> 1, c0 = (tid & 1) * 64;

  for (int kc = 0; kc < 2; ++kc) {
    const int k0 = kc * 128;
    const float* asrc = emb + (size_t)tokl[rr] * 256 + k0 + c0;
    const float* bsrc = wih + (size_t)((rr >> 5) * 256 + u0 + (rr & 31)) * 256 + k0 + c0;
    u16* adst = Al + rr * 136 + c0;
    u16* bdst = Bl + rr * 136 + c0;
    #pragma unroll
    for (int gdx = 0; gdx < 8; ++gdx) {
      f32x4 a0 = *(const f32x4*)(asrc + gdx * 8);
      f32x4 a1 = *(const f32x4*)(asrc + gdx * 8 + 4);
      *(short8*)(adst + gdx * 8) = pack8(a0, a1);
      f32x4 b0 = *(const f32x4*)(bsrc + gdx * 8);
      f32x4 b1 = *(const f32x4*)(bsrc + gdx * 8 + 4);
      *(short8*)(bdst + gdx * 8) = pack8(b0, b1);
    }
    __syncthreads();
    #pragma unroll
    for (int ks = 0; ks < 4; ++ks) {
      short8 af[4], bfr[4];
      #pragma unroll
      for (int i = 0; i < 4; ++i)
        af[i] = *(const short8*)(Al + (mh + i * 16 + fr) * 136 + ks * 32 + fq * 8);
      #pragma unroll
      for (int j = 0; j < 4; ++j)
        bfr[j] = *(const short8*)(Bl + (nh + j * 16 + fr) * 136 + ks * 32 + fq * 8);
      #pragma unroll
      for (int i = 0; i < 4; ++i)
        #pragma unroll
        for (int j = 0; j < 4; ++j)
          acc[i][j] = __builtin_amdgcn_mfma_f32_16x16x32_bf16(af[i], bfr[j], acc[i][j], 0, 0, 0);
    }
    __syncthreads();
  }

  // epilogue: 8x 16-B stores/lane; each 64-B line owned by this block.
  const int g0 = nh >> 5;                 // gates {g0, g0+1}, g0 in {0,2}
  const int mh4 = mh >> 2;
  const int tid2 = (u0 >> 5) * 64 + qb * 16 + fr;   // lstm thread id
  u16* xbase = xgf + ((size_t)(d * 4 + g) * 512) * 16384;
  #pragma unroll
  for (int i = 0; i < 4; ++i) {
    const int s = s0 + mh4 + i * 4 + fq;
    #pragma unroll
    for (int nsub = 0; nsub < 2; ++nsub) {
      const int j0 = nsub, j1 = nsub + 2;
      const int cA = nh + j0 * 16 + fr, cB = nh + j1 * 16 + fr;
      short8 sv;
      #pragma unroll
      for (int r = 0; r < 4; ++r) {
        float vA = acc[i][j0][r] + biasl[cA];
        if (g0 == 2) vA *= 2.0f;            // gate 2 pre-doubled (tanh form)
        float vB = acc[i][j1][r] + biasl[cB];
        sv[r]     = (short)f2bf(vA);
        sv[4 + r] = (short)f2bf(vB);
      }
      *(short8*)(xbase + (size_t)s * 16384 + tid2 * 32 + nsub * 16 + g0 * 4) = sv;
    }
  }
}

// ---- one LSTM timestep; CB reads h_{t-1}, PW receives h_t (compile-time) ----
template<int CB, int PW>
__device__ __forceinline__ void lstm_step(
    int T, int d, int l, int q, int n, int w, int tid,
    const long long (&wreg)[2][4][8], float (&cst)[2][4],
    uint4& X0, uint4& X1, uint4& X2, uint4& X3,
    uint8_t* hx, const u16* xsl, u16* hhb)
{
  const int t_eff = d ? (511 - T) : T;

  // top-of-step prefetch for T+2 (whole step to land; no barrier drain)
  int tn = T + 2; if (tn > 511) tn = 511;
  const int sn = d ? (511 - tn) : tn;
  const uint4* pf = (const uint4*)(xsl + (size_t)sn * 16384);
  const uint4 P0 = pf[0], P1 = pf[1], P2 = pf[2], P3 = pf[3];

  // A fragments from hx[CB]: lane -> m = l&15, k = kt*32 + q*8 + j
  const uint8_t* hr = hx + CB * 4224 + (l & 15) * 264 + q * 8;
  long long a0 = *(const long long*)(hr + 0);
  long long a1 = *(const long long*)(hr + 32);
  long long a2 = *(const long long*)(hr + 64);
  long long a3 = *(const long long*)(hr + 96);
  long long a4 = *(const long long*)(hr + 128);
  long long a5 = *(const long long*)(hr + 160);
  long long a6 = *(const long long*)(hr + 192);
  long long a7 = *(const long long*)(hr + 224);

  // MFMA: 2 unit-blocks x 4 gates x 8 K-chunks
  f32x4 acc[2][4];
  #pragma unroll
  for (int ubi = 0; ubi < 2; ++ubi)
    #pragma unroll
    for (int gate = 0; gate < 4; ++gate) {
      f32x4 a = {0.f, 0.f, 0.f, 0.f};
      a = __builtin_amdgcn_mfma_f32_16x16x32_fp8_fp8(a0, wreg[ubi][gate][0], a, 0, 0, 0);
      a = __builtin_amdgcn_mfma_f32_16x16x32_fp8_fp8(a1, wreg[ubi][gate][1], a, 0, 0, 0);
      a = __builtin_amdgcn_mfma_f32_16x16x32_fp8_fp8(a2, wreg[ubi][gate][2], a, 0, 0, 0);
      a = __builtin_amdgcn_mfma_f32_16x16x32_fp8_fp8(a3, wreg[ubi][gate][3], a, 0, 0, 0);
      a = __builtin_amdgcn_mfma_f32_16x16x32_fp8_fp8(a4, wreg[ubi][gate][4], a, 0, 0, 0);
      a = __builtin_amdgcn_mfma_f32_16x16x32_fp8_fp8(a5, wreg[ubi][gate][5], a, 0, 0, 0);
      a = __builtin_amdgcn_mfma_f32_16x16x32_fp8_fp8(a6, wreg[ubi][gate][6], a, 0, 0, 0);
      a = __builtin_amdgcn_mfma_f32_16x16x32_fp8_fp8(a7, wreg[ubi][gate][7], a, 0, 0, 0);
      acc[ubi][gate] = a;
    }

  // gate math; lane = batches m=q*4+r, units u = w*32 + ubi*16 + n
  const float S1 = 1.0f / 256.0f;
  const float S2 = 2.0f / 256.0f;
  float hsc[2][4];
  uint32_t hist[2][4];
  #pragma unroll
  for (int ubi = 0; ubi < 2; ++ubi) {
    const uint4& Xa = ubi ? X2 : X0;   // gates 0,1 (r0..3 each)
    const uint4& Xb = ubi ? X3 : X1;   // gates 2,3
    #pragma unroll
    for (int r = 0; r < 4; ++r) {
      const uint32_t wi = (r < 2) ? Xa.x : Xa.y;
      const uint32_t wf = (r < 2) ? Xa.z : Xa.w;
      const uint32_t wg = (r < 2) ? Xb.x : Xb.y;
      const uint32_t wo = (r < 2) ? Xb.z : Xb.w;
      const int hp = r & 1;
      const float iv = fmaf(acc[ubi][0][r], S1, bfh(wi, hp));
      const float fv = fmaf(acc[ubi][1][r], S1, bfh(wf, hp));
      const float gv = fmaf(acc[ubi][2][r], S2, bfh(wg, hp));   // pre-doubled
      const float ov = fmaf(acc[ubi][3][r], S1, bfh(wo, hp));
      const float si = __builtin_amdgcn_rcpf(1.0f + __expf(-iv));
      const float sf = __builtin_amdgcn_rcpf(1.0f + __expf(-fv));
      const float so = __builtin_amdgcn_rcpf(1.0f + __expf(-ov));
      const float tg = 1.0f - 2.0f * __builtin_amdgcn_rcpf(1.0f + __expf(gv));
      const float c  = sf * cst[ubi][r] + si * tg;
      cst[ubi][r] = c;
      const float th = 1.0f - 2.0f * __builtin_amdgcn_rcpf(1.0f + __expf(2.0f * c));
      const float hv = so * th;
      hsc[ubi][r]  = hv * 16.0f;
      hist[ubi][r] = (uint32_t)f2bf(hv);
    }
  }
  // commit prefetch (X regs now free)
  X0 = P0; X1 = P1; X2 = P2; X3 = P3;

  // publish h as fp8 pairs into hx[PW] at pi-order: byte k = w*32 + 2n + ubi
  {
    uint8_t* hw = hx + PW * 4224 + w * 32 + 2 * n;
    #pragma unroll
    for (int r = 0; r < 4; ++r) {
      const int pk = __builtin_amdgcn_cvt_pk_fp8_f32(hsc[0][r], hsc[1][r], 0, false);
      *(u16*)(hw + (q * 4 + r) * 264) = (u16)(pk & 0xffff);
    }
  }
  __syncthreads();

  // bf16 history AFTER the barrier — drains under next step's MFMAs
  {
    u16* hhs = hhb + (size_t)t_eff * 256;
    #pragma unroll
    for (int ubi = 0; ubi < 2; ++ubi)
      #pragma unroll
      for (int r = 0; r < 4; ++r)
        hhs[(size_t)(q * 4 + r) * 512 * 256 + ubi * 16] = (u16)hist[ubi][r];
  }
}

// ---- self-contained BiLSTM: 8 WGs = dir(2) x batch-group(4 of 16) ----
// 512 threads = 8 waves; wave w owns units [32w,32w+32) x 4 gates in regs/AGPRs.
__global__ void __launch_bounds__(512, 2) lstm_kernel(
    const u16* __restrict__ xgf, const uint8_t* __restrict__ wfrag,
    u16* __restrict__ hhist)
{
  __shared__ uint8_t hx[2 * 16 * 264];   // fp8 h double-buffer, stride 264

  const int tid = threadIdx.x;
  const int bid = blockIdx.x;            // 0..7
  const int d = bid >> 2, g = bid & 3;
  const int w = tid >> 6, l = tid & 63;
  const int n = l & 15, q = l >> 4;

  // register/AGPR-resident fp8 weight fragments (128 regs)
  long long wreg[2][4][8];
  {
    const uint8_t* wb = wfrag + ((size_t)(d * 8 + w) * 2) * 4 * 8 * 64 * 8;
    #pragma unroll
    for (int ubi = 0; ubi < 2; ++ubi)
      #pragma unroll
      for (int gate = 0; gate < 4; ++gate)
        #pragma unroll
        for (int kt = 0; kt < 8; ++kt)
          wreg[ubi][gate][kt] =
            *(const long long*)(wb + ((((size_t)(ubi * 4 + gate) * 8) + kt) * 64 + l) * 8);
  }

  for (int i = tid; i < 2112; i += 512) ((uint32_t*)hx)[i] = 0u;  // h_{-1}=0 (both bufs)

  const u16* xsl = xgf + (size_t)(d * 4 + g) * 512 * 16384 + (size_t)tid * 32;
  float cst[2][4] = {};
  u16* hhb = hhist + ((size_t)(d * 64 + g * 16) * 512) * 256 + (w * 32 + n);

  // preload xg for t=0 (X) and t=1 (Y)
  uint4 X0, X1, X2, X3, Y0, Y1, Y2, Y3;
  {
    const uint4* p0 = (const uint4*)(xsl + (size_t)(d ? 511 : 0) * 16384);
    X0 = p0[0]; X1 = p0[1]; X2 = p0[2]; X3 = p0[3];
    const uint4* p1 = (const uint4*)(xsl + (size_t)(d ? 510 : 1) * 16384);
    Y0 = p1[0]; Y1 = p1[1]; Y2 = p1[2]; Y3 = p1[3];
  }
  __syncthreads();

  for (int tt = 0; tt < 512; tt += 2) {
    lstm_step<0, 1>(tt,     d, l, q, n, w, tid, wreg, cst, X0, X1, X2, X3, hx, xsl, hhb);
    lstm_step<1, 0>(tt + 1, d, l, q, n, w, tid, wreg, cst, Y0, Y1, Y2, Y3, hx, xsl, hhb);
  }
}

// ---- feats = [hf|hb] @ w_out^T + b_out ----
__global__ void __launch_bounds__(256) proj_kernel(
    const u16* __restrict__ hhist, const float* __restrict__ w_out,
    const float* __restrict__ b_out, float* __restrict__ feats)
{
  __shared__ float wsm[9 * 512];
  __shared__ float bsm[9];
  const int tid = threadIdx.x;
  for (int i = tid; i < 4608; i += 256) wsm[i] = w_out[i];
  if (tid < 9) bsm[tid] = b_out[tid];
  __syncthreads();

  const int wv = tid >> 6, l = tid & 63;
  const int gw = blockIdx.x * 4 + wv;
  const int jb = l * 8;
  const int dd = jb >> 8;
  const int jloc = jb & 255;

  for (int qq = 0; qq < 8; ++qq) {
    const int pos = gw * 8 + qq;
    const int b = pos >> 9, s = pos & 511;
    const u16* hp = hhist + ((size_t)(dd * 64 + b) * 512 + s) * 256 + jloc;
    short8 hv8 = *(const short8*)hp;
    float hf[8];
    #pragma unroll
    for (int j = 0; j < 8; ++j) hf[j] = bf2f((u16)hv8[j]);
    float pt[9];
    #pragma unroll
    for (int tg2 = 0; tg2 < 9; ++tg2) {
      const float* wr = wsm + tg2 * 512 + jb;
      float a = 0.f;
      #pragma unroll
      for (int j = 0; j < 8; ++j) a = fmaf(hf[j], wr[j], a);
      pt[tg2] = a;
    }
    #pragma unroll
    for (int tg2 = 0; tg2 < 9; ++tg2)
      #pragma unroll
      for (int off = 32; off; off >>= 1)
        pt[tg2] += __shfl_xor(pt[tg2], off, 64);
    if (l == 0) {
      float* fo = feats + (size_t)pos * 9;
      #pragma unroll
      for (int tg2 = 0; tg2 < 9; ++tg2) fo[tg2] = pt[tg2] + bsm[tg2];
    }
  }
}

// ---- CRF NLL ----
__global__ void __launch_bounds__(64) crf_kernel(
    const float* __restrict__ feats, const int* __restrict__ tags,
    const float* __restrict__ strans, const float* __restrict__ etrans,
    const float* __restrict__ trans, float* out)
{
  __shared__ float em[512 * 9];
  __shared__ float tr[81];
  __shared__ int   tg[512];
  const int b = blockIdx.x, l = threadIdx.x;
  const float* fb = feats + (size_t)b * 512 * 9;
  for (int i = l; i < 4608; i += 64) em[i] = fb[i];
  for (int i = l; i < 512; i += 64) tg[i] = tags[b * 512 + i];
  if (l < 81) tr[l] = trans[l];
  __syncthreads();

  float sc = 0.f;
  for (int s = 1 + l; s < 512; s += 64)
    sc += tr[tg[s - 1] * 9 + tg[s]] + em[s * 9 + tg[s]];
  #pragma unroll
  for (int off = 32; off; off >>= 1) sc += __shfl_xor(sc, off, 64);
  const float score = sc + strans[tg[0]] + em[tg[0]] + etrans[tg[511]];

  const int jj = (l < 9) ? l : 0;
  float al = (l < 9) ? (strans[l] + em[l]) : -1e30f;
  for (int t = 1; t < 512; ++t) {
    float ai[9];
    #pragma unroll
    for (int i = 0; i < 9; ++i) ai[i] = __shfl(al, i, 64);
    float m = ai[0];
    #pragma unroll
    for (int i = 1; i < 9; ++i) m = fmaxf(m, ai[i]);
    float ssum = 0.f;
    #pragma unroll
    for (int i = 0; i < 9; ++i) ssum += __expf(ai[i] + tr[i * 9 + jj] - m);
    al = em[t * 9 + jj] + m + __logf(ssum);
  }
  float v = (l < 9) ? (al + etrans[l]) : -3.0e38f;
  float m2 = v;
  #pragma unroll
  for (int off = 32; off; off >>= 1) m2 = fmaxf(m2, __shfl_xor(m2, off, 64));
  float ex = (l < 9) ? __expf(v - m2) : 0.f;
  #pragma unroll
  for (int off = 32; off; off >>= 1) ex += __shfl_xor(ex, off, 64);
  const float logZ = m2 + __logf(ex);
  if (l == 0) atomicAdd(out, -(score - logZ) * (1.0f / 64.0f));
}

extern "C" void kernel_launch(void* const* d_in, const int* in_sizes, int n_in,
                              void* d_out, int out_size, void* d_ws, size_t ws_size,
                              hipStream_t stream) {
  (void)in_sizes; (void)n_in; (void)out_size; (void)ws_size;
  const int*   sent = (const int*)d_in[0];
  const int*   tags = (const int*)d_in[1];
  const float* emb  = (const float*)d_in[3];
  const float* wihf = (const float*)d_in[4];
  const float* whhf = (const float*)d_in[5];
  const float* bihf = (const float*)d_in[6];
  const float* bhhf = (const float*)d_in[7];
  const float* wihb = (const float*)d_in[8];
  const float* whhb = (const float*)d_in[9];
  const float* bihb = (const float*)d_in[10];
  const float* bhhb = (const float*)d_in[11];
  const float* wout = (const float*)d_in[12];
  const float* bout = (const float*)d_in[13];
  const float* strn = (const float*)d_in[14];
  const float* etrn = (const float*)d_in[15];
  const float* trn  = (const float*)d_in[16];

  char* ws = (char*)d_ws;
  float*   biasb = (float*)(ws + OFF_BIAS);
  uint8_t* wfrag = (uint8_t*)(ws + OFF_WFRAG);
  u16*     hhist = (u16*)(ws + OFF_HHIST);
  float*   feats = (float*)(ws + OFF_FEATS);
  u16*     xgf   = (u16*)(ws + OFF_XG);
  float*   out   = (float*)d_out;

  hipMemsetAsync(d_out, 0, sizeof(float), stream);

  hipFuncSetAttribute(reinterpret_cast<const void*>(xg_gemm_kernel),
                      hipFuncAttributeMaxDynamicSharedMemorySize, 70656);

  bias_kernel<<<8, 256, 0, stream>>>(bihf, bhhf, bihb, bhhb, biasb);
  wfrag_prep_kernel<<<128, 256, 0, stream>>>(whhf, whhb, wfrag);
  xg_gemm_kernel<<<dim3(16, 256), 256, 70656, stream>>>(sent, emb, wihf, wihb, biasb, xgf);
  lstm_kernel<<<8, 512, 0, stream>>>(xgf, wfrag, hhist);
  proj_kernel<<<1024, 256, 0, stream>>>(hhist, wout, bout, feats);
  crf_kernel<<<64, 64, 0, stream>>>(feats, tags, strn, etrn, trn, out);
}